// Round 17
// baseline (323.794 us; speedup 1.0000x reference)
//
#include <hip/hip_runtime.h>
#include <stdint.h>

#define BB 256
#define TT 2048
#define KK 64
#define CHUNK 64
#define NCHUNK (TT / CHUNK)   // 32
#define WARM 32
#define NSEG 16
#define SEGLEN (TT / NSEG)    // 128

typedef float f32x4 __attribute__((ext_vector_type(4)));

__device__ __forceinline__ unsigned umax3(unsigned a, unsigned b, unsigned c) {
    return max(max(a, b), c);   // v_max3_u32
}

// LDS-only barrier: never drains vmcnt (bp stores / feat prefetch stay in flight)
__device__ __forceinline__ void lds_barrier() {
    asm volatile("s_waitcnt lgkmcnt(0)\n\ts_barrier" ::: "memory");
}

// ============================ kernel 1: forward ============================
// grid 4096 x 128 threads: block = (batch b = idx>>4, segment s = idx&15).
// 2 waves; lane l of BOTH waves owns tag-row l (fv replicated per wave).
// Wave w covers predecessors p in [32w, 32w+32): 32 v_readlane (fv broadcast,
// VALU pipe) + 32 v_add of pre-baked fixed-point keys
//   trk[i] = (round(clamp(tr,-256)*2048) << 6) | (63 - p)
// -> one u32 max = max AND first-argmax. Cross-wave merge = 4B/lane via LDS.
// launch_bounds(128, 4): cap = 128 VGPR so the allocator can keep trk resident
// (under the (128,8)/64-cap it spilled everything -> VGPR=32, R15/R16 failure).
// If the compiler lands <=64 VGPR we still get 8 waves/SIMD at runtime.
__global__ __launch_bounds__(128, 4)
void viterbi_fwd_pm(const float* __restrict__ feats,
                    const float* __restrict__ trans,
                    const int* __restrict__ start_tag_p,
                    const int* __restrict__ stop_tag_p,
                    float* __restrict__ out,
                    unsigned char* __restrict__ bp_ws)
{
    const int bid  = blockIdx.x;
    const int b    = bid >> 4;
    const int s    = bid & 15;
    const int t0   = s * SEGLEN - (s ? WARM : 0);
    const int warmN = s ? WARM : 0;
    const int L    = warmN + SEGLEN;          // 128 or 160
    const int tid  = threadIdx.x;
    const int lane = tid & 63;
    const int w    = __builtin_amdgcn_readfirstlane(tid >> 6);  // 0..1
    const int pb   = w * 32;                  // this wave's p-base (SGPR)

    const int start_tag = *start_tag_p;
    const int stop_tag  = *stop_tag_p;

    __shared__ int part[2][2][KK];            // [buf][wave][row] partial keys (1KB)

    const float* fb = feats + (size_t)b * TT * KK + (size_t)t0 * KK + lane;
    unsigned char* bpb = bp_ws + (size_t)b * TT * KK;

    // ---- load transition slice via volatile asm (non-rematerializable) ----
    f32x4 tv[8];
    {
        const float* ap = &trans[lane * KK + pb];
#pragma unroll
        for (int q = 0; q < 8; ++q)
            asm volatile("global_load_dwordx4 %0, %1, off"
                         : "=v"(tv[q]) : "v"(ap + q * 4));
        asm volatile("s_waitcnt vmcnt(0)" ::: "memory");
    }
    // bake packed fixed-point keys (sources are asm outputs -> must stay live)
    int trk[32];
#pragma unroll
    for (int q = 0; q < 8; ++q) {
#pragma unroll
        for (int e = 0; e < 4; ++e) {
            const int i = q * 4 + e;
            const float c = fmaxf(tv[q][e], -256.0f);            // soft -inf
            trk[i] = (((int)rintf(c * 2048.0f)) << 6) | (63 - (pb + i));
        }
    }

    // fv init (positive domain, fixed-point (value*2048)<<6)
    int fv = ((s || lane == start_tag) ? (2048 * 2048) : (512 * 2048)) << 6;

    // feat prefetch ring (depth 4), coalesced 256B/wave
    float r0 = fb[0 * KK], r1 = fb[1 * KK], r2 = fb[2 * KK], r3 = fb[3 * KK];

    auto stepf = [&](int tau, float featval, bool st) {
        const int fvb = fv;
        unsigned a0 = 0u, a1 = 0u, a2 = 0u, a3 = 0u;
#pragma unroll
        for (int i = 0; i < 32; i += 4) {
            const int s0 = __builtin_amdgcn_readlane(fvb, pb + i + 0);
            const int s1 = __builtin_amdgcn_readlane(fvb, pb + i + 1);
            const int s2 = __builtin_amdgcn_readlane(fvb, pb + i + 2);
            const int s3 = __builtin_amdgcn_readlane(fvb, pb + i + 3);
            const unsigned c0 = (unsigned)(s0 + trk[i + 0]);
            const unsigned c1 = (unsigned)(s1 + trk[i + 1]);
            const unsigned c2 = (unsigned)(s2 + trk[i + 2]);
            const unsigned c3 = (unsigned)(s3 + trk[i + 3]);
            a0 = umax3(a0, c0, c1);
            a1 = umax3(a1, c2, c3);
            const unsigned t = a0; a0 = a2; a2 = t;   // rotate roles: 4-deep ILP
            const unsigned u = a1; a1 = a3; a3 = u;
        }
        const unsigned kl = umax3(max(a0, a1), a2, a3);

        part[tau & 1][w][lane] = kl;          // 4B/lane, conflict-free
        lds_barrier();
        const unsigned K = max(kl, (unsigned)part[tau & 1][w ^ 1][lane]);

        if (st && w == 0)
            bpb[(size_t)(t0 + tau) * KK + lane] = (unsigned char)(63 - (K & 63u));

        fv = (int)(K & 0xFFFFFFC0u) + (((int)rintf(featval * 2048.0f)) << 6);
    };

    // warm steps (no bp stores); warmN is 0 or 32, multiple of 4
    for (int tau = 0; tau < warmN; tau += 4) {
        float n0 = fb[(tau + 4) * KK]; stepf(tau + 0, r0, false); r0 = n0;
        float n1 = fb[(tau + 5) * KK]; stepf(tau + 1, r1, false); r1 = n1;
        float n2 = fb[(tau + 6) * KK]; stepf(tau + 2, r2, false); r2 = n2;
        float n3 = fb[(tau + 7) * KK]; stepf(tau + 3, r3, false); r3 = n3;
    }
    // owned steps (bp stores)
    for (int tau = warmN; tau < L; tau += 4) {
        float n0 = fb[min(tau + 4, L - 1) * KK]; stepf(tau + 0, r0, true); r0 = n0;
        float n1 = fb[min(tau + 5, L - 1) * KK]; stepf(tau + 1, r1, true); r1 = n1;
        float n2 = fb[min(tau + 6, L - 1) * KK]; stepf(tau + 2, r2, true); r2 = n2;
        float n3 = fb[min(tau + 7, L - 1) * KK]; stepf(tau + 3, r3, true); r3 = n3;
    }

    // terminal argmax (last segment): uniform warm offset cancels in argmax;
    // true score recomputed from the decoded path in kernel 2.
    if (s == NSEG - 1 && w == 0) {
        const float fvf = (float)(fv >> 6) * (1.0f / 2048.0f);
        float bv = fvf + trans[stop_tag * KK + lane];
        int bi = lane;
#pragma unroll
        for (int off = 1; off < 64; off <<= 1) {
            const float ov = __shfl_xor(bv, off);
            const int   oi = __shfl_xor(bi, off);
            const bool take = (ov > bv) || (ov == bv && oi < bi);
            bv = take ? ov : bv;
            bi = take ? oi : bi;
        }
        if (lane == 0) out[b] = (float)bi;   // carrier for bestlast -> k2
    }
}

// ====================== kernel 2: backtrace + score ======================
__global__ __launch_bounds__(512)
void viterbi_bt_score(const float* __restrict__ feats,
                      const float* __restrict__ trans,
                      const int* __restrict__ start_tag_p,
                      const int* __restrict__ stop_tag_p,
                      float* __restrict__ out,
                      const unsigned char* __restrict__ bp_ws)
{
    const int b    = blockIdx.x;
    const int tid  = threadIdx.x;
    const int lane = tid & 63;
    const int w    = __builtin_amdgcn_readfirstlane(tid >> 6);  // 0..7

    __shared__ int cmap[NCHUNK][KK];
    __shared__ int be_lds[NCHUNK];
    __shared__ unsigned char path_lds[TT];
    __shared__ float red_lds[8];

    const unsigned char* bpb = bp_ws + (size_t)b * TT * KK;

    // ---- chunk-map composition: wave w composes chunks 4w..4w+3 ----
    {
        const int c0 = w * 4;
        const unsigned char* q0 = bpb + (size_t)(c0 + 0) * CHUNK * KK + lane;
        const unsigned char* q1 = bpb + (size_t)(c0 + 1) * CHUNK * KK + lane;
        const unsigned char* q2 = bpb + (size_t)(c0 + 2) * CHUNK * KK + lane;
        const unsigned char* q3 = bpb + (size_t)(c0 + 3) * CHUNK * KK + lane;
        int M0 = lane, M1 = lane, M2 = lane, M3 = lane;
        int a0 = q0[0], a1 = q1[0], a2 = q2[0], a3 = q3[0];
        int b0 = q0[KK], b1 = q1[KK], b2 = q2[KK], b3 = q3[KK];
        for (int t = 0; t < CHUNK; t += 2) {
            int n0 = 0, n1 = 0, n2 = 0, n3 = 0, m0 = 0, m1 = 0, m2 = 0, m3 = 0;
            if (t + 2 < CHUNK) {
                n0 = q0[(t + 2) * KK]; n1 = q1[(t + 2) * KK];
                n2 = q2[(t + 2) * KK]; n3 = q3[(t + 2) * KK];
                m0 = q0[(t + 3) * KK]; m1 = q1[(t + 3) * KK];
                m2 = q2[(t + 3) * KK]; m3 = q3[(t + 3) * KK];
            }
            M0 = __shfl(M0, a0); M1 = __shfl(M1, a1);
            M2 = __shfl(M2, a2); M3 = __shfl(M3, a3);
            M0 = __shfl(M0, b0); M1 = __shfl(M1, b1);
            M2 = __shfl(M2, b2); M3 = __shfl(M3, b3);
            a0 = n0; a1 = n1; a2 = n2; a3 = n3;
            b0 = m0; b1 = m1; b2 = m2; b3 = m3;
        }
        cmap[c0 + 0][lane] = M0; cmap[c0 + 1][lane] = M1;
        cmap[c0 + 2][lane] = M2; cmap[c0 + 3][lane] = M3;
    }
    __syncthreads();

    // ---- chunk-boundary tags (serial, 32 LDS hops) ----
    if (tid == 0) {
        int x = (int)out[b];          // bestlast from k1
        be_lds[NCHUNK - 1] = x;
        for (int c = NCHUNK - 1; c >= 1; --c) {
            x = cmap[c][x];
            be_lds[c - 1] = x;
        }
    }
    __syncthreads();

    // ---- parallel interior backtrace (32 chunks), also fill path_lds ----
    if (tid < NCHUNK) {
        const int c = tid;
        int x = be_lds[c];
        float* po = out + BB + (size_t)b * TT;
        for (int t = (c + 1) * CHUNK - 1; t >= c * CHUNK; --t) {
            po[t] = (float)x;
            path_lds[t] = (unsigned char)x;
            x = (int)bpb[(size_t)t * KK + x];
        }
    }
    __syncthreads();

    // ---- exact score recompute along the decoded path ----
    const float* fbb = feats + (size_t)b * TT * KK;
    const int start_tag = *start_tag_p;
    const int stop_tag  = *stop_tag_p;
    float acc = 0.0f;
    for (int t = tid; t < TT; t += 512) {
        const int xt = path_lds[t];
        const int xp = (t > 0) ? (int)path_lds[t - 1] : start_tag;
        acc += fbb[(size_t)t * KK + xt] + trans[xt * KK + xp];
    }
    if (tid == 0) acc += trans[stop_tag * KK + (int)path_lds[TT - 1]];
#pragma unroll
    for (int off = 1; off < 64; off <<= 1) acc += __shfl_xor(acc, off);
    if (lane == 0) red_lds[w] = acc;
    __syncthreads();
    if (tid == 0) {
        float sc = 0.0f;
        for (int i = 0; i < 8; ++i) sc += red_lds[i];
        out[b] = sc;
    }
}

extern "C" void kernel_launch(void* const* d_in, const int* in_sizes, int n_in,
                              void* d_out, int out_size, void* d_ws, size_t ws_size,
                              hipStream_t stream) {
    const float* feats = (const float*)d_in[0];
    const float* trans = (const float*)d_in[1];
    const int* start_tag = (const int*)d_in[2];
    const int* stop_tag  = (const int*)d_in[3];
    float* out = (float*)d_out;
    unsigned char* bp = (unsigned char*)d_ws;   // B*T*K = 33.5 MB backpointers

    viterbi_fwd_pm<<<BB * NSEG, 128, 0, stream>>>(feats, trans, start_tag, stop_tag, out, bp);
    viterbi_bt_score<<<BB, 512, 0, stream>>>(feats, trans, start_tag, stop_tag, out, bp);
}

// Round 18
// 209.168 us; speedup vs baseline: 1.5480x; 1.5480x over previous
//
#include <hip/hip_runtime.h>
#include <stdint.h>

#define BB 256
#define TT 2048
#define KK 64
#define CHUNK 64
#define NCHUNK (TT / CHUNK)   // 32
#define WLEN 16
#define WARM 32               // 2 windows
#define NSEG 16
#define SEGLEN (TT / NSEG)    // 128
#define NEG_INF_F (-10000.0f)

#define DPP_XOR1 0xB1   // quad_perm [1,0,3,2]

template <int CTRL>
__device__ __forceinline__ unsigned dpp_max_u(unsigned x) {
    int d = __builtin_amdgcn_update_dpp(0, (int)x, CTRL, 0xF, 0xF, true);
    return max(x, (unsigned)d);
}
__device__ __forceinline__ unsigned umax3(unsigned a, unsigned b, unsigned c) {
    return max(max(a, b), c);   // v_max3_u32
}

// LDS-only barrier: never drains vmcnt (bp stores / window loads stay in flight)
__device__ __forceinline__ void lds_barrier() {
    asm volatile("s_waitcnt lgkmcnt(0)\n\ts_barrier" ::: "memory");
}

__device__ __forceinline__ void gload_lds16(const void* g, void* l) {
    __builtin_amdgcn_global_load_lds(
        (const __attribute__((address_space(1))) void*)g,
        (__attribute__((address_space(3))) void*)l, 16, 0, 0);
}

// ============================ kernel 1: forward ============================
// grid 4096 x 128 threads: block = (batch b = idx>>4, segment s = idx&15).
// 2 waves/block; lane layout: row n = w*32 + (lane>>1), p-slice j = lane&1
// owning p in [j*32, j*32+32). Positive-domain fv; trans clamped at -256.
// Packed key: value-bits & ~31 | (31 - local_idx) -> one u32 max = max+argmax.
// This is the proven R13 configuration (209 us): fwd is at the LDS-b128
// throughput roofline (16 ds_read_b128 / block-step, ~12 cyc each).
__global__ __launch_bounds__(128, 8)
void viterbi_fwd_seg(const float* __restrict__ feats,
                     const float* __restrict__ trans,
                     const int* __restrict__ start_tag_p,
                     const int* __restrict__ stop_tag_p,
                     float* __restrict__ out,
                     unsigned char* __restrict__ bp_ws)
{
    const int bid  = blockIdx.x;
    const int b    = bid >> 4;
    const int s    = bid & 15;
    const int t0   = s * SEGLEN - (s ? WARM : 0);
    const int NW   = (SEGLEN + (s ? WARM : 0)) / WLEN;   // 8 or 10
    const int WWARM = s ? (WARM / WLEN) : 0;             // 2 or 0

    const int tid  = threadIdx.x;
    const int lane = tid & 63;
    const int w    = __builtin_amdgcn_readfirstlane(tid >> 6);  // wave 0..1
    const int g    = lane >> 1;        // row within wave (32 rows/wave)
    const int j    = lane & 1;         // p-slice within row (2 x 32)
    const int n    = w * 32 + g;       // owned output row
    const int pbase = j * 32;
    const bool jz  = (j == 0);

    const int start_tag = *start_tag_p;
    const int stop_tag  = *stop_tag_p;

    __shared__ float fv_lds[2][KK];          // double-buffered state (positive domain)
    __shared__ float feat_lds[2][WLEN][KK];  // 8KB feat window double buffer

    const float* fb0 = feats + (size_t)b * TT * KK + (size_t)t0 * KK;
    unsigned char* bpb = bp_ws + (size_t)b * TT * KK;

    // async window stage: wave w fills its 2KB slice, 2 x 1KB issues (linear)
    auto issue_win = [&](int widx, int bufsel) {
        const char* gsrc = (const char*)(fb0 + (size_t)widx * WLEN * KK)
                         + w * 2048 + lane * 16;
        char* ldst = (char*)&feat_lds[bufsel][0][0] + w * 2048;
        gload_lds16(gsrc, ldst);
        gload_lds16(gsrc + 1024, ldst + 1024);
    };
    issue_win(0, 0);

    // per-lane transition fragment trans[n][pbase..pbase+31], soft-inf clamped
    const float4* trp = (const float4*)&trans[n * KK + pbase];
    float4 tr[8];
#pragma unroll
    for (int q = 0; q < 8; ++q) {
        tr[q] = trp[q];
        tr[q].x = fmaxf(tr[q].x, -256.0f);
        tr[q].y = fmaxf(tr[q].y, -256.0f);
        tr[q].z = fmaxf(tr[q].z, -256.0f);
        tr[q].w = fmaxf(tr[q].w, -256.0f);
    }
    const float tstop = trans[stop_tag * KK + lane];

    if (tid < KK)
        fv_lds[0][tid] = s ? 2048.0f
                           : ((tid == start_tag) ? 2048.0f : 512.0f);

    __syncthreads();   // drains vmcnt(0): window 0 resident + fv init visible
    issue_win(1, 1);

#define KEY5(x, inv) ((unsigned)((__float_as_int(x) & 0xFFFFFFE0) | (inv)))

    auto step = [&](int tau, const float* frow, bool st) {
        const float4* fp = (const float4*)&fv_lds[tau & 1][pbase];
        const float featval = frow[n];     // 2-lane broadcast, conflict-free

        // half 0: local idx 0..15 (inv 31..16), computed then reduced (caps VGPRs)
        unsigned kl;
        {
            const float4 f0 = fp[0], f1 = fp[1], f2 = fp[2], f3 = fp[3];
            const unsigned k0  = KEY5(f0.x + tr[0].x, 31);
            const unsigned k1  = KEY5(f0.y + tr[0].y, 30);
            const unsigned k2  = KEY5(f0.z + tr[0].z, 29);
            const unsigned k3  = KEY5(f0.w + tr[0].w, 28);
            const unsigned k4  = KEY5(f1.x + tr[1].x, 27);
            const unsigned k5  = KEY5(f1.y + tr[1].y, 26);
            const unsigned k6  = KEY5(f1.z + tr[1].z, 25);
            const unsigned k7  = KEY5(f1.w + tr[1].w, 24);
            const unsigned k8  = KEY5(f2.x + tr[2].x, 23);
            const unsigned k9  = KEY5(f2.y + tr[2].y, 22);
            const unsigned k10 = KEY5(f2.z + tr[2].z, 21);
            const unsigned k11 = KEY5(f2.w + tr[2].w, 20);
            const unsigned k12 = KEY5(f3.x + tr[3].x, 19);
            const unsigned k13 = KEY5(f3.y + tr[3].y, 18);
            const unsigned k14 = KEY5(f3.z + tr[3].z, 17);
            const unsigned k15 = KEY5(f3.w + tr[3].w, 16);
            const unsigned m0 = umax3(k0, k1, k2);
            const unsigned m1 = umax3(k3, k4, k5);
            const unsigned m2 = umax3(k6, k7, k8);
            const unsigned m3 = umax3(k9, k10, k11);
            const unsigned m4 = umax3(k12, k13, k14);
            kl = max(umax3(umax3(m0, m1, m2), m3, m4), k15);
        }
        // half 1: local idx 16..31 (inv 15..0)
        {
            const float4 f4 = fp[4], f5 = fp[5], f6 = fp[6], f7 = fp[7];
            const unsigned k0  = KEY5(f4.x + tr[4].x, 15);
            const unsigned k1  = KEY5(f4.y + tr[4].y, 14);
            const unsigned k2  = KEY5(f4.z + tr[4].z, 13);
            const unsigned k3  = KEY5(f4.w + tr[4].w, 12);
            const unsigned k4  = KEY5(f5.x + tr[5].x, 11);
            const unsigned k5  = KEY5(f5.y + tr[5].y, 10);
            const unsigned k6  = KEY5(f5.z + tr[5].z,  9);
            const unsigned k7  = KEY5(f5.w + tr[5].w,  8);
            const unsigned k8  = KEY5(f6.x + tr[6].x,  7);
            const unsigned k9  = KEY5(f6.y + tr[6].y,  6);
            const unsigned k10 = KEY5(f6.z + tr[6].z,  5);
            const unsigned k11 = KEY5(f6.w + tr[6].w,  4);
            const unsigned k12 = KEY5(f7.x + tr[7].x,  3);
            const unsigned k13 = KEY5(f7.y + tr[7].y,  2);
            const unsigned k14 = KEY5(f7.z + tr[7].z,  1);
            const unsigned k15 = KEY5(f7.w + tr[7].w,  0);
            const unsigned m0 = umax3(k0, k1, k2);
            const unsigned m1 = umax3(k3, k4, k5);
            const unsigned m2 = umax3(k6, k7, k8);
            const unsigned m3 = umax3(k9, k10, k11);
            const unsigned m4 = umax3(k12, k13, k14);
            kl = max(kl, max(umax3(umax3(m0, m1, m2), m3, m4), k15));
        }

        // row reduce (2 lanes)
        const unsigned K = dpp_max_u<DPP_XOR1>(kl);

        // fv update (truncated max value + feat)
        if (jz) fv_lds[(tau + 1) & 1][n] =
            __int_as_float((int)(K & 0xFFFFFFE0u)) + featval;

        if (st) {
            // winner lane (j=0 preferred), local idx from key low bits
            const unsigned long long mb = __ballot(kl == K);
            const unsigned pr = (unsigned)(mb >> (lane & 62)) & 3u;
            const int jq = __ffs((int)pr) - 1;
            const int iq = 31 - (int)(K & 31u);
            const int p = (jq << 5) | iq;
            if (jz) bpb[(size_t)(t0 + tau) * KK + n] = (unsigned char)p;
        }
        lds_barrier();
    };

    for (int W = 0; W < NW; ++W) {
        const float (*fw)[KK] = feat_lds[W & 1];
        const bool st = (W >= WWARM);
        const int base = W * WLEN;
        for (int tt = 0; tt < WLEN; tt += 4) {
            step(base + tt + 0, fw[tt + 0], st);
            step(base + tt + 1, fw[tt + 1], st);
            step(base + tt + 2, fw[tt + 2], st);
            step(base + tt + 3, fw[tt + 3], st);
        }
        // boundary: window W+1 (issued one window ago) must be resident
        asm volatile("s_waitcnt vmcnt(0)" ::: "memory");
        __builtin_amdgcn_s_barrier();
        if (W + 2 < NW) issue_win(W + 2, W & 1);   // overwrite just-read buffer
    }

    // terminal argmax (last segment): uniform offset cancels in argmax;
    // true score recomputed from the decoded path in kernel 2.
    if (s == NSEG - 1 && w == 0) {
        float bv = fv_lds[(SEGLEN + WARM) & 1][lane] + tstop;  // 160 even -> buf 0
        int bi = lane;
#pragma unroll
        for (int off = 1; off < 64; off <<= 1) {
            const float ov = __shfl_xor(bv, off);
            const int   oi = __shfl_xor(bi, off);
            const bool take = (ov > bv) || (ov == bv && oi < bi);
            bv = take ? ov : bv;
            bi = take ? oi : bi;
        }
        if (lane == 0) out[b] = (float)bi;   // carrier for bestlast -> k2
    }
}

// ====================== kernel 2: backtrace + score ======================
__global__ __launch_bounds__(512)
void viterbi_bt_score(const float* __restrict__ feats,
                      const float* __restrict__ trans,
                      const int* __restrict__ start_tag_p,
                      const int* __restrict__ stop_tag_p,
                      float* __restrict__ out,
                      const unsigned char* __restrict__ bp_ws)
{
    const int b    = blockIdx.x;
    const int tid  = threadIdx.x;
    const int lane = tid & 63;
    const int w    = __builtin_amdgcn_readfirstlane(tid >> 6);  // 0..7

    __shared__ int cmap[NCHUNK][KK];
    __shared__ int be_lds[NCHUNK];
    __shared__ unsigned char path_lds[TT];
    __shared__ float red_lds[8];

    const unsigned char* bpb = bp_ws + (size_t)b * TT * KK;

    // ---- chunk-map composition: wave w composes chunks 4w..4w+3 ----
    {
        const int c0 = w * 4;
        const unsigned char* q0 = bpb + (size_t)(c0 + 0) * CHUNK * KK + lane;
        const unsigned char* q1 = bpb + (size_t)(c0 + 1) * CHUNK * KK + lane;
        const unsigned char* q2 = bpb + (size_t)(c0 + 2) * CHUNK * KK + lane;
        const unsigned char* q3 = bpb + (size_t)(c0 + 3) * CHUNK * KK + lane;
        int M0 = lane, M1 = lane, M2 = lane, M3 = lane;
        int a0 = q0[0], a1 = q1[0], a2 = q2[0], a3 = q3[0];
        int b0 = q0[KK], b1 = q1[KK], b2 = q2[KK], b3 = q3[KK];
        for (int t = 0; t < CHUNK; t += 2) {
            int n0 = 0, n1 = 0, n2 = 0, n3 = 0, m0 = 0, m1 = 0, m2 = 0, m3 = 0;
            if (t + 2 < CHUNK) {
                n0 = q0[(t + 2) * KK]; n1 = q1[(t + 2) * KK];
                n2 = q2[(t + 2) * KK]; n3 = q3[(t + 2) * KK];
                m0 = q0[(t + 3) * KK]; m1 = q1[(t + 3) * KK];
                m2 = q2[(t + 3) * KK]; m3 = q3[(t + 3) * KK];
            }
            M0 = __shfl(M0, a0); M1 = __shfl(M1, a1);
            M2 = __shfl(M2, a2); M3 = __shfl(M3, a3);
            M0 = __shfl(M0, b0); M1 = __shfl(M1, b1);
            M2 = __shfl(M2, b2); M3 = __shfl(M3, b3);
            a0 = n0; a1 = n1; a2 = n2; a3 = n3;
            b0 = m0; b1 = m1; b2 = m2; b3 = m3;
        }
        cmap[c0 + 0][lane] = M0; cmap[c0 + 1][lane] = M1;
        cmap[c0 + 2][lane] = M2; cmap[c0 + 3][lane] = M3;
    }
    __syncthreads();

    // ---- chunk-boundary tags (serial, 32 LDS hops) ----
    if (tid == 0) {
        int x = (int)out[b];          // bestlast from k1
        be_lds[NCHUNK - 1] = x;
        for (int c = NCHUNK - 1; c >= 1; --c) {
            x = cmap[c][x];
            be_lds[c - 1] = x;
        }
    }
    __syncthreads();

    // ---- parallel interior backtrace (32 chunks), also fill path_lds ----
    if (tid < NCHUNK) {
        const int c = tid;
        int x = be_lds[c];
        float* po = out + BB + (size_t)b * TT;
        for (int t = (c + 1) * CHUNK - 1; t >= c * CHUNK; --t) {
            po[t] = (float)x;
            path_lds[t] = (unsigned char)x;
            x = (int)bpb[(size_t)t * KK + x];
        }
    }
    __syncthreads();

    // ---- exact score recompute along the decoded path ----
    const float* fbb = feats + (size_t)b * TT * KK;
    const int start_tag = *start_tag_p;
    const int stop_tag  = *stop_tag_p;
    float acc = 0.0f;
    for (int t = tid; t < TT; t += 512) {
        const int xt = path_lds[t];
        const int xp = (t > 0) ? (int)path_lds[t - 1] : start_tag;
        acc += fbb[(size_t)t * KK + xt] + trans[xt * KK + xp];
    }
    if (tid == 0) acc += trans[stop_tag * KK + (int)path_lds[TT - 1]];
#pragma unroll
    for (int off = 1; off < 64; off <<= 1) acc += __shfl_xor(acc, off);
    if (lane == 0) red_lds[w] = acc;
    __syncthreads();
    if (tid == 0) {
        float sc = 0.0f;
        for (int i = 0; i < 8; ++i) sc += red_lds[i];
        out[b] = sc;
    }
}

extern "C" void kernel_launch(void* const* d_in, const int* in_sizes, int n_in,
                              void* d_out, int out_size, void* d_ws, size_t ws_size,
                              hipStream_t stream) {
    const float* feats = (const float*)d_in[0];
    const float* trans = (const float*)d_in[1];
    const int* start_tag = (const int*)d_in[2];
    const int* stop_tag  = (const int*)d_in[3];
    float* out = (float*)d_out;
    unsigned char* bp = (unsigned char*)d_ws;   // B*T*K = 33.5 MB backpointers

    viterbi_fwd_seg<<<BB * NSEG, 128, 0, stream>>>(feats, trans, start_tag, stop_tag, out, bp);
    viterbi_bt_score<<<BB, 512, 0, stream>>>(feats, trans, start_tag, stop_tag, out, bp);
}

// Round 20
// 208.570 us; speedup vs baseline: 1.5525x; 1.0029x over previous
//
#include <hip/hip_runtime.h>
#include <stdint.h>

#define BB 256
#define TT 2048
#define KK 64
#define CHUNK 64
#define NCHUNK (TT / CHUNK)   // 32
#define WLEN 16
#define WARM 32               // 2 windows
#define NSEG 16
#define SEGLEN (TT / NSEG)    // 128
#define NEG_INF_F (-10000.0f)

#define DPP_XOR1 0xB1   // quad_perm [1,0,3,2]

template <int CTRL>
__device__ __forceinline__ unsigned dpp_max_u(unsigned x) {
    int d = __builtin_amdgcn_update_dpp(0, (int)x, CTRL, 0xF, 0xF, true);
    return max(x, (unsigned)d);
}
__device__ __forceinline__ unsigned umax3(unsigned a, unsigned b, unsigned c) {
    return max(max(a, b), c);   // v_max3_u32
}

// LDS-only barrier: never drains vmcnt (bp stores / window loads stay in flight)
__device__ __forceinline__ void lds_barrier() {
    asm volatile("s_waitcnt lgkmcnt(0)\n\ts_barrier" ::: "memory");
}

__device__ __forceinline__ void gload_lds16(const void* g, void* l) {
    __builtin_amdgcn_global_load_lds(
        (const __attribute__((address_space(1))) void*)g,
        (__attribute__((address_space(3))) void*)l, 16, 0, 0);
}

// ============================ kernel 1: forward ============================
// R13 configuration (209 us) + ONE change: the 32 transition values are held
// as SCALAR floats pinned loop-carried with 32-bit "+v" asm (the float4 tie
// failed to compile in R19). The compiler can no longer rematerialize/reload
// them from L1 each step (VGPR_Count=32 proved it was doing exactly that).
__global__ __launch_bounds__(128, 8)
void viterbi_fwd_seg(const float* __restrict__ feats,
                     const float* __restrict__ trans,
                     const int* __restrict__ start_tag_p,
                     const int* __restrict__ stop_tag_p,
                     float* __restrict__ out,
                     unsigned char* __restrict__ bp_ws)
{
    const int bid  = blockIdx.x;
    const int b    = bid >> 4;
    const int s    = bid & 15;
    const int t0   = s * SEGLEN - (s ? WARM : 0);
    const int NW   = (SEGLEN + (s ? WARM : 0)) / WLEN;   // 8 or 10
    const int WWARM = s ? (WARM / WLEN) : 0;             // 2 or 0

    const int tid  = threadIdx.x;
    const int lane = tid & 63;
    const int w    = __builtin_amdgcn_readfirstlane(tid >> 6);  // wave 0..1
    const int g    = lane >> 1;        // row within wave (32 rows/wave)
    const int j    = lane & 1;         // p-slice within row (2 x 32)
    const int n    = w * 32 + g;       // owned output row
    const int pbase = j * 32;
    const bool jz  = (j == 0);

    const int start_tag = *start_tag_p;
    const int stop_tag  = *stop_tag_p;

    __shared__ float fv_lds[2][KK];          // double-buffered state (positive domain)
    __shared__ float feat_lds[2][WLEN][KK];  // 8KB feat window double buffer

    const float* fb0 = feats + (size_t)b * TT * KK + (size_t)t0 * KK;
    unsigned char* bpb = bp_ws + (size_t)b * TT * KK;

    // async window stage: wave w fills its 2KB slice, 2 x 1KB issues (linear)
    auto issue_win = [&](int widx, int bufsel) {
        const char* gsrc = (const char*)(fb0 + (size_t)widx * WLEN * KK)
                         + w * 2048 + lane * 16;
        char* ldst = (char*)&feat_lds[bufsel][0][0] + w * 2048;
        gload_lds16(gsrc, ldst);
        gload_lds16(gsrc + 1024, ldst + 1024);
    };
    issue_win(0, 0);

    // per-lane transition fragment trans[n][pbase..pbase+31], soft-inf clamped,
    // unpacked to 32 scalar floats (pinnable as 32-bit "+v")
    float trs[32];
    {
        const float4* trp = (const float4*)&trans[n * KK + pbase];
#pragma unroll
        for (int q = 0; q < 8; ++q) {
            const float4 v = trp[q];
            trs[q * 4 + 0] = fmaxf(v.x, -256.0f);
            trs[q * 4 + 1] = fmaxf(v.y, -256.0f);
            trs[q * 4 + 2] = fmaxf(v.z, -256.0f);
            trs[q * 4 + 3] = fmaxf(v.w, -256.0f);
        }
    }
    const float tstop = trans[stop_tag * KK + lane];

    if (tid < KK)
        fv_lds[0][tid] = s ? 2048.0f
                           : ((tid == start_tag) ? 2048.0f : 512.0f);

    __syncthreads();   // drains vmcnt(0): window 0 resident + fv init visible
    issue_win(1, 1);

#define KEY5(x, inv) ((unsigned)((__float_as_int(x) & 0xFFFFFFE0) | (inv)))

    auto step = [&](int tau, const float* frow, bool st) {
        // loop-carried scalar pins: trs may be "modified" here each step ->
        // cannot be rematerialized from trans; must stay in VGPRs.
#pragma unroll
        for (int i = 0; i < 32; ++i)
            asm volatile("" : "+v"(trs[i]));

        const float4* fp = (const float4*)&fv_lds[tau & 1][pbase];
        const float featval = frow[n];     // 2-lane broadcast, conflict-free

        // half 0: local idx 0..15 (inv 31..16), computed then reduced (caps VGPRs)
        unsigned kl;
        {
            const float4 f0 = fp[0], f1 = fp[1], f2 = fp[2], f3 = fp[3];
            const unsigned k0  = KEY5(f0.x + trs[0],  31);
            const unsigned k1  = KEY5(f0.y + trs[1],  30);
            const unsigned k2  = KEY5(f0.z + trs[2],  29);
            const unsigned k3  = KEY5(f0.w + trs[3],  28);
            const unsigned k4  = KEY5(f1.x + trs[4],  27);
            const unsigned k5  = KEY5(f1.y + trs[5],  26);
            const unsigned k6  = KEY5(f1.z + trs[6],  25);
            const unsigned k7  = KEY5(f1.w + trs[7],  24);
            const unsigned k8  = KEY5(f2.x + trs[8],  23);
            const unsigned k9  = KEY5(f2.y + trs[9],  22);
            const unsigned k10 = KEY5(f2.z + trs[10], 21);
            const unsigned k11 = KEY5(f2.w + trs[11], 20);
            const unsigned k12 = KEY5(f3.x + trs[12], 19);
            const unsigned k13 = KEY5(f3.y + trs[13], 18);
            const unsigned k14 = KEY5(f3.z + trs[14], 17);
            const unsigned k15 = KEY5(f3.w + trs[15], 16);
            const unsigned m0 = umax3(k0, k1, k2);
            const unsigned m1 = umax3(k3, k4, k5);
            const unsigned m2 = umax3(k6, k7, k8);
            const unsigned m3 = umax3(k9, k10, k11);
            const unsigned m4 = umax3(k12, k13, k14);
            kl = max(umax3(umax3(m0, m1, m2), m3, m4), k15);
        }
        // half 1: local idx 16..31 (inv 15..0)
        {
            const float4 f4 = fp[4], f5 = fp[5], f6 = fp[6], f7 = fp[7];
            const unsigned k0  = KEY5(f4.x + trs[16], 15);
            const unsigned k1  = KEY5(f4.y + trs[17], 14);
            const unsigned k2  = KEY5(f4.z + trs[18], 13);
            const unsigned k3  = KEY5(f4.w + trs[19], 12);
            const unsigned k4  = KEY5(f5.x + trs[20], 11);
            const unsigned k5  = KEY5(f5.y + trs[21], 10);
            const unsigned k6  = KEY5(f5.z + trs[22],  9);
            const unsigned k7  = KEY5(f5.w + trs[23],  8);
            const unsigned k8  = KEY5(f6.x + trs[24],  7);
            const unsigned k9  = KEY5(f6.y + trs[25],  6);
            const unsigned k10 = KEY5(f6.z + trs[26],  5);
            const unsigned k11 = KEY5(f6.w + trs[27],  4);
            const unsigned k12 = KEY5(f7.x + trs[28],  3);
            const unsigned k13 = KEY5(f7.y + trs[29],  2);
            const unsigned k14 = KEY5(f7.z + trs[30],  1);
            const unsigned k15 = KEY5(f7.w + trs[31],  0);
            const unsigned m0 = umax3(k0, k1, k2);
            const unsigned m1 = umax3(k3, k4, k5);
            const unsigned m2 = umax3(k6, k7, k8);
            const unsigned m3 = umax3(k9, k10, k11);
            const unsigned m4 = umax3(k12, k13, k14);
            kl = max(kl, max(umax3(umax3(m0, m1, m2), m3, m4), k15));
        }

        // row reduce (2 lanes)
        const unsigned K = dpp_max_u<DPP_XOR1>(kl);

        // fv update (truncated max value + feat)
        if (jz) fv_lds[(tau + 1) & 1][n] =
            __int_as_float((int)(K & 0xFFFFFFE0u)) + featval;

        if (st) {
            // winner lane (j=0 preferred), local idx from key low bits
            const unsigned long long mb = __ballot(kl == K);
            const unsigned pr = (unsigned)(mb >> (lane & 62)) & 3u;
            const int jq = __ffs((int)pr) - 1;
            const int iq = 31 - (int)(K & 31u);
            const int p = (jq << 5) | iq;
            if (jz) bpb[(size_t)(t0 + tau) * KK + n] = (unsigned char)p;
        }
        lds_barrier();
    };

    for (int W = 0; W < NW; ++W) {
        const float (*fw)[KK] = feat_lds[W & 1];
        const bool st = (W >= WWARM);
        const int base = W * WLEN;
        for (int tt = 0; tt < WLEN; tt += 4) {
            step(base + tt + 0, fw[tt + 0], st);
            step(base + tt + 1, fw[tt + 1], st);
            step(base + tt + 2, fw[tt + 2], st);
            step(base + tt + 3, fw[tt + 3], st);
        }
        // boundary: window W+1 (issued one window ago) must be resident
        asm volatile("s_waitcnt vmcnt(0)" ::: "memory");
        __builtin_amdgcn_s_barrier();
        if (W + 2 < NW) issue_win(W + 2, W & 1);   // overwrite just-read buffer
    }

    // terminal argmax (last segment): uniform offset cancels in argmax;
    // true score recomputed from the decoded path in kernel 2.
    if (s == NSEG - 1 && w == 0) {
        float bv = fv_lds[(SEGLEN + WARM) & 1][lane] + tstop;  // 160 even -> buf 0
        int bi = lane;
#pragma unroll
        for (int off = 1; off < 64; off <<= 1) {
            const float ov = __shfl_xor(bv, off);
            const int   oi = __shfl_xor(bi, off);
            const bool take = (ov > bv) || (ov == bv && oi < bi);
            bv = take ? ov : bv;
            bi = take ? oi : bi;
        }
        if (lane == 0) out[b] = (float)bi;   // carrier for bestlast -> k2
    }
}

// ====================== kernel 2: backtrace + score ======================
__global__ __launch_bounds__(512)
void viterbi_bt_score(const float* __restrict__ feats,
                      const float* __restrict__ trans,
                      const int* __restrict__ start_tag_p,
                      const int* __restrict__ stop_tag_p,
                      float* __restrict__ out,
                      const unsigned char* __restrict__ bp_ws)
{
    const int b    = blockIdx.x;
    const int tid  = threadIdx.x;
    const int lane = tid & 63;
    const int w    = __builtin_amdgcn_readfirstlane(tid >> 6);  // 0..7

    __shared__ int cmap[NCHUNK][KK];
    __shared__ int be_lds[NCHUNK];
    __shared__ unsigned char path_lds[TT];
    __shared__ float red_lds[8];

    const unsigned char* bpb = bp_ws + (size_t)b * TT * KK;

    // ---- chunk-map composition: wave w composes chunks 4w..4w+3 ----
    {
        const int c0 = w * 4;
        const unsigned char* q0 = bpb + (size_t)(c0 + 0) * CHUNK * KK + lane;
        const unsigned char* q1 = bpb + (size_t)(c0 + 1) * CHUNK * KK + lane;
        const unsigned char* q2 = bpb + (size_t)(c0 + 2) * CHUNK * KK + lane;
        const unsigned char* q3 = bpb + (size_t)(c0 + 3) * CHUNK * KK + lane;
        int M0 = lane, M1 = lane, M2 = lane, M3 = lane;
        int a0 = q0[0], a1 = q1[0], a2 = q2[0], a3 = q3[0];
        int b0 = q0[KK], b1 = q1[KK], b2 = q2[KK], b3 = q3[KK];
        for (int t = 0; t < CHUNK; t += 2) {
            int n0 = 0, n1 = 0, n2 = 0, n3 = 0, m0 = 0, m1 = 0, m2 = 0, m3 = 0;
            if (t + 2 < CHUNK) {
                n0 = q0[(t + 2) * KK]; n1 = q1[(t + 2) * KK];
                n2 = q2[(t + 2) * KK]; n3 = q3[(t + 2) * KK];
                m0 = q0[(t + 3) * KK]; m1 = q1[(t + 3) * KK];
                m2 = q2[(t + 3) * KK]; m3 = q3[(t + 3) * KK];
            }
            M0 = __shfl(M0, a0); M1 = __shfl(M1, a1);
            M2 = __shfl(M2, a2); M3 = __shfl(M3, a3);
            M0 = __shfl(M0, b0); M1 = __shfl(M1, b1);
            M2 = __shfl(M2, b2); M3 = __shfl(M3, b3);
            a0 = n0; a1 = n1; a2 = n2; a3 = n3;
            b0 = m0; b1 = m1; b2 = m2; b3 = m3;
        }
        cmap[c0 + 0][lane] = M0; cmap[c0 + 1][lane] = M1;
        cmap[c0 + 2][lane] = M2; cmap[c0 + 3][lane] = M3;
    }
    __syncthreads();

    // ---- chunk-boundary tags (serial, 32 LDS hops) ----
    if (tid == 0) {
        int x = (int)out[b];          // bestlast from k1
        be_lds[NCHUNK - 1] = x;
        for (int c = NCHUNK - 1; c >= 1; --c) {
            x = cmap[c][x];
            be_lds[c - 1] = x;
        }
    }
    __syncthreads();

    // ---- parallel interior backtrace (32 chunks), also fill path_lds ----
    if (tid < NCHUNK) {
        const int c = tid;
        int x = be_lds[c];
        float* po = out + BB + (size_t)b * TT;
        for (int t = (c + 1) * CHUNK - 1; t >= c * CHUNK; --t) {
            po[t] = (float)x;
            path_lds[t] = (unsigned char)x;
            x = (int)bpb[(size_t)t * KK + x];
        }
    }
    __syncthreads();

    // ---- exact score recompute along the decoded path ----
    const float* fbb = feats + (size_t)b * TT * KK;
    const int start_tag = *start_tag_p;
    const int stop_tag  = *stop_tag_p;
    float acc = 0.0f;
    for (int t = tid; t < TT; t += 512) {
        const int xt = path_lds[t];
        const int xp = (t > 0) ? (int)path_lds[t - 1] : start_tag;
        acc += fbb[(size_t)t * KK + xt] + trans[xt * KK + xp];
    }
    if (tid == 0) acc += trans[stop_tag * KK + (int)path_lds[TT - 1]];
#pragma unroll
    for (int off = 1; off < 64; off <<= 1) acc += __shfl_xor(acc, off);
    if (lane == 0) red_lds[w] = acc;
    __syncthreads();
    if (tid == 0) {
        float sc = 0.0f;
        for (int i = 0; i < 8; ++i) sc += red_lds[i];
        out[b] = sc;
    }
}

extern "C" void kernel_launch(void* const* d_in, const int* in_sizes, int n_in,
                              void* d_out, int out_size, void* d_ws, size_t ws_size,
                              hipStream_t stream) {
    const float* feats = (const float*)d_in[0];
    const float* trans = (const float*)d_in[1];
    const int* start_tag = (const int*)d_in[2];
    const int* stop_tag  = (const int*)d_in[3];
    float* out = (float*)d_out;
    unsigned char* bp = (unsigned char*)d_ws;   // B*T*K = 33.5 MB backpointers

    viterbi_fwd_seg<<<BB * NSEG, 128, 0, stream>>>(feats, trans, start_tag, stop_tag, out, bp);
    viterbi_bt_score<<<BB, 512, 0, stream>>>(feats, trans, start_tag, stop_tag, out, bp);
}